// Round 2
// baseline (636.664 us; speedup 1.0000x reference)
//
#include <hip/hip_runtime.h>
#include <hip/hip_bf16.h>
#include <math.h>

// Shapes (fixed by setup_inputs): B=4, N=16384, V=6, C=384, H=W=32,
// bn hidden J=64, fused D=32, clusters K=64, out O=256.
#define B_ 4
#define N_ 16384
#define V_ 6
#define C_ 384
#define H_ 32
#define W_ 32
#define HW_ 1024
#define J_ 64
#define D_ 32
#define K_ 64
#define O_ 256

__device__ __forceinline__ float gelu_f(float x){
  return 0.5f * x * (1.0f + erff(x * 0.70710678118654752440f));
}
__device__ __forceinline__ float sigmoid_f(float x){
  return 1.0f / (1.0f + expf(-x));
}
__device__ __forceinline__ float wsum64(float v){
  #pragma unroll
  for (int m = 1; m < 64; m <<= 1) v += __shfl_xor(v, m);
  return v;
}
__device__ __forceinline__ float wmax64(float v){
  #pragma unroll
  for (int m = 1; m < 64; m <<= 1) v = fmaxf(v, __shfl_xor(v, m));
  return v;
}
__device__ __forceinline__ float wsum32(float v){
  #pragma unroll
  for (int m = 1; m < 32; m <<= 1) v += __shfl_xor(v, m);
  return v;
}

// ---------------- K0: proj[bv][pix][j] = sum_c vf[bv][c][pix] * w1[c][j] ----
// grid = 24 bv * 16 pixel-tiles of 64; block = 256
__global__ __launch_bounds__(256) void k0_proj(
    const float* __restrict__ vf, const float* __restrict__ w1,
    float* __restrict__ proj)
{
  const int bv   = blockIdx.x >> 4;
  const int pix0 = (blockIdx.x & 15) * 64;
  __shared__ float fs[128][65];            // padded: avoid 16-way conflicts
  const int t = threadIdx.x;
  const int j = t & 63;
  const int pr = t >> 6;                   // 0..3 pixel-group
  float acc[16];
  #pragma unroll
  for (int i = 0; i < 16; ++i) acc[i] = 0.f;

  for (int c0 = 0; c0 < C_; c0 += 128){
    #pragma unroll
    for (int i = 0; i < 32; ++i){
      int idx = t + i * 256;               // 0..8191
      int cl = idx >> 6, px = idx & 63;
      fs[cl][px] = vf[((size_t)bv * C_ + (c0 + cl)) * HW_ + pix0 + px];
    }
    __syncthreads();
    for (int cl = 0; cl < 128; ++cl){
      float w = w1[(c0 + cl) * 64 + j];    // coalesced across lanes
      const float* row = &fs[cl][pr * 16]; // uniform per wave -> LDS broadcast
      #pragma unroll
      for (int i = 0; i < 16; ++i) acc[i] += row[i] * w;
    }
    __syncthreads();
  }
  #pragma unroll
  for (int i = 0; i < 16; ++i)
    proj[((size_t)bv * HW_ + pix0 + pr * 16 + i) * 64 + j] = acc[i];
}

// ---------------- K1: per-point fused projection + NetVLAD activations -----
// grid = B*N/4 blocks; block = 256 (4 waves, one point per wave)
__global__ __launch_bounds__(256) void k1_points(
    const float* __restrict__ xyz, const float* __restrict__ g14d,
    const float* __restrict__ ext, const float* __restrict__ intr,
    const float* __restrict__ offs, const unsigned char* __restrict__ mask,
    const float* __restrict__ gw1, const float* __restrict__ gb1,
    const float* __restrict__ gw2, const float* __restrict__ gb2,
    const float* __restrict__ proj, const float* __restrict__ b1,
    const float* __restrict__ w2, const float* __restrict__ b2,
    const float* __restrict__ lnw, const float* __restrict__ lnb,
    const float* __restrict__ cw, const float* __restrict__ ln1w,
    const float* __restrict__ ln1b,
    float* __restrict__ fused_out, float* __restrict__ act_out)
{
  __shared__ float h_s[4][64];
  __shared__ float f_s[4][32];
  const int wave = threadIdx.x >> 6, lane = threadIdx.x & 63;
  const int p = (blockIdx.x << 2) + wave;       // global point index
  const int b = p >> 14;                        // N = 2^14

  // ---- physics gate (all lanes redundantly; tiny) ----
  const float* g = g14d + (size_t)p * 14;
  float in0 = fminf(fmaxf(g[4],  0.01f), 10.f);
  float in1 = fminf(fmaxf(g[5],  0.01f), 10.f);
  float in2 = fminf(fmaxf(g[6],  0.01f), 10.f);
  float in3 = fminf(fmaxf(g[11], 0.0f),  1.f);
  float gacc = gb2[0];
  #pragma unroll
  for (int hh = 0; hh < 16; ++hh){
    float tv = gb1[hh] + in0 * gw1[hh] + in1 * gw1[16 + hh]
             + in2 * gw1[32 + hh] + in3 * gw1[48 + hh];
    gacc += gelu_f(tv) * gw2[hh];
  }
  const float gate = sigmoid_f(gacc);

  const float px = xyz[p * 3], py = xyz[p * 3 + 1], pz = xyz[p * 3 + 2];
  const float offx = offs[p * 2], offy = offs[p * 2 + 1];
  const float mval = mask[p] ? 1.f : 0.f;
  const int d = lane & 31, half = lane >> 5;

  float sum_f = 0.f, sum_m = 0.f;
  for (int v = 0; v < V_; ++v){
    const float* E = ext  + (size_t)(b * V_ + v) * 12;
    const float* I = intr + (size_t)(b * V_ + v) * 9;
    float c0 = E[0]*px + E[1]*py + E[2]*pz + E[3];
    float c1 = E[4]*px + E[5]*py + E[6]*pz + E[7];
    float c2 = E[8]*px + E[9]*py + E[10]*pz + E[11];
    float u0 = I[0]*c0 + I[1]*c1 + I[2]*c2;
    float u1 = I[3]*c0 + I[4]*c1 + I[5]*c2;
    float u2 = I[6]*c0 + I[7]*c1 + I[8]*c2;
    float depth = fmaxf(u2, 1e-6f);
    float gx = 2.0f * (u0 / depth) / (W_ * 14.0f) - 1.0f + offx;
    float gy = 2.0f * (u1 / depth) / (H_ * 14.0f) - 1.0f + offy;
    float fx = ((gx + 1.0f) * W_ - 1.0f) * 0.5f;
    float fy = ((gy + 1.0f) * H_ - 1.0f) * 0.5f;
    // clamp to keep int conversion defined; any clamped point has no valid texel
    fx = fminf(fmaxf(fx, -4.0f), 36.0f);
    fy = fminf(fmaxf(fy, -4.0f), 36.0f);
    float fx0 = floorf(fx), fy0 = floorf(fy);
    float wx = fx - fx0, wy = fy - fy0;
    int x0 = (int)fx0, y0 = (int)fy0;
    const float* pr = proj + (size_t)(b * V_ + v) * HW_ * 64;
    float s = 0.f;
    {
      float wt = (1.f - wx) * (1.f - wy);
      if (x0 >= 0 && x0 < W_ && y0 >= 0 && y0 < H_)
        s += wt * pr[(y0 * W_ + x0) * 64 + lane];
      wt = wx * (1.f - wy);
      if (x0 + 1 >= 0 && x0 + 1 < W_ && y0 >= 0 && y0 < H_)
        s += wt * pr[(y0 * W_ + x0 + 1) * 64 + lane];
      wt = (1.f - wx) * wy;
      if (x0 >= 0 && x0 < W_ && y0 + 1 >= 0 && y0 + 1 < H_)
        s += wt * pr[((y0 + 1) * W_ + x0) * 64 + lane];
      wt = wx * wy;
      if (x0 + 1 >= 0 && x0 + 1 < W_ && y0 + 1 >= 0 && y0 + 1 < H_)
        s += wt * pr[((y0 + 1) * W_ + x0 + 1) * 64 + lane];
    }
    h_s[wave][lane] = gelu_f(s + b1[lane]);
    __syncthreads();
    // 64x32 matmul split across the two 32-lane halves
    float yp = 0.f;
    const float* hrow = h_s[wave] + half * 32;
    #pragma unroll
    for (int j = 0; j < 32; ++j) yp += hrow[j] * w2[(half * 32 + j) * 32 + d];
    float yv = yp + __shfl_xor(yp, 32) + b2[d];
    // LN over 32 dims (both halves hold identical copies)
    float mean = wsum32(yv) * (1.f / 32.f);
    float dv = yv - mean;
    float var = wsum32(dv * dv) * (1.f / 32.f);
    float v32 = dv * rsqrtf(var + 1e-5f) * lnw[d] + lnb[d];
    float vm = (depth > 0.1f && fabsf(gx) <= 1.0f && fabsf(gy) <= 1.0f) ? mval : 0.f;
    sum_f += v32 * gate * vm;
    sum_m += vm;
    __syncthreads();
  }
  float fu = sum_f / (sum_m + 1e-6f);
  if (lane < 32){
    f_s[wave][lane] = fu;
    fused_out[(size_t)p * 32 + lane] = fu;
  }
  __syncthreads();
  // act = softmax(LN(fused @ cw)) * mask ; lane = cluster k
  float z = 0.f;
  #pragma unroll
  for (int dd = 0; dd < 32; ++dd) z += f_s[wave][dd] * cw[dd * 64 + lane];
  float mean = wsum64(z) * (1.f / 64.f);
  float dz = z - mean;
  float var = wsum64(dz * dz) * (1.f / 64.f);
  float zl = dz * rsqrtf(var + 1e-5f) * ln1w[lane] + ln1b[lane];
  float mx = wmax64(zl);
  float e = expf(zl - mx);
  float ssum = wsum64(e);
  act_out[(size_t)p * 64 + lane] = (e / ssum) * mval;
}

// ---------------- K2: vlad[b,d,k] += sum_n act*fused ; asum[b,k] += act ----
// grid = B * 64 segments (256 points each); block = 256
__global__ __launch_bounds__(256) void k2_vlad(
    const float* __restrict__ fused, const float* __restrict__ act,
    float* __restrict__ vlad_acc, float* __restrict__ asum_acc)
{
  __shared__ float act_s[64][64];
  __shared__ float fu_s[64][32];
  const int b = blockIdx.x >> 6, seg = blockIdx.x & 63;
  const int n0 = seg * 256;
  const int t = threadIdx.x, k = t & 63, dg = t >> 6;
  float vacc[8];
  #pragma unroll
  for (int r = 0; r < 8; ++r) vacc[r] = 0.f;
  float asum = 0.f;

  for (int sc = 0; sc < 4; ++sc){
    int nb = n0 + sc * 64;
    #pragma unroll
    for (int i = 0; i < 16; ++i){
      int idx = t + i * 256;
      act_s[idx >> 6][idx & 63] =
        act[((size_t)((b << 14) + nb + (idx >> 6))) * 64 + (idx & 63)];
    }
    #pragma unroll
    for (int i = 0; i < 8; ++i){
      int idx = t + i * 256;
      fu_s[idx >> 5][idx & 31] =
        fused[((size_t)((b << 14) + nb + (idx >> 5))) * 32 + (idx & 31)];
    }
    __syncthreads();
    for (int i = 0; i < 64; ++i){
      float a = act_s[i][k];               // lane-consecutive, conflict-free
      const float* fr = &fu_s[i][dg * 8];  // uniform per wave -> broadcast
      #pragma unroll
      for (int r = 0; r < 8; ++r) vacc[r] += a * fr[r];
      if (dg == 0) asum += a;
    }
    __syncthreads();
  }
  #pragma unroll
  for (int r = 0; r < 8; ++r)
    atomicAdd(&vlad_acc[b * 2048 + (dg * 8 + r) * 64 + k], vacc[r]);
  if (dg == 0) atomicAdd(&asum_acc[b * 64 + k], asum);
}

// ---------------- K3: finalize per batch --------------------------------
__global__ __launch_bounds__(256) void k3_final(
    const float* __restrict__ vlad_acc, const float* __restrict__ asum_acc,
    const float* __restrict__ cw2, const float* __restrict__ hw,
    const float* __restrict__ gww, const float* __restrict__ glnw,
    const float* __restrict__ glnb, float* __restrict__ outp)
{
  const int b = blockIdx.x, t = threadIdx.x;
  __shared__ float vs[2048];
  __shared__ float denom[64];
  __shared__ float redA[4], redB[4], redC[4];
  __shared__ float out_s[256];

  #pragma unroll
  for (int i = 0; i < 8; ++i){
    int idx = t + i * 256;
    vs[idx] = vlad_acc[b * 2048 + idx]
            - asum_acc[b * 64 + (idx & 63)] * cw2[idx];
  }
  __syncthreads();
  if (t < 64){
    float ss = 0.f;
    #pragma unroll
    for (int dd = 0; dd < 32; ++dd){ float x = vs[dd * 64 + t]; ss += x * x; }
    denom[t] = fmaxf(sqrtf(ss), 1e-12f);
  }
  __syncthreads();
  float ls = 0.f;
  #pragma unroll
  for (int i = 0; i < 8; ++i){
    int idx = t + i * 256;
    float x = vs[idx] / denom[idx & 63];
    vs[idx] = x;
    ls += x * x;
  }
  ls = wsum64(ls);
  if ((t & 63) == 0) redA[t >> 6] = ls;
  __syncthreads();
  float tot = redA[0] + redA[1] + redA[2] + redA[3];
  float ginv = 1.0f / fmaxf(sqrtf(tot), 1e-12f);
  // out = (vlad/gnorm) @ hw
  float acc = 0.f;
  for (int idx = 0; idx < 2048; ++idx)
    acc += vs[idx] * hw[(size_t)idx * 256 + t];
  float o = acc * ginv;
  out_s[t] = o;
  __syncthreads();
  // gates = sigmoid(LN(out @ gw))
  float gp = 0.f;
  for (int i = 0; i < 256; ++i) gp += out_s[i] * gww[i * 256 + t];
  float s1 = wsum64(gp);
  if ((t & 63) == 0) redB[t >> 6] = s1;
  __syncthreads();
  float mean = (redB[0] + redB[1] + redB[2] + redB[3]) * (1.f / 256.f);
  float dv = gp - mean;
  float s2 = wsum64(dv * dv);
  if ((t & 63) == 0) redC[t >> 6] = s2;
  __syncthreads();
  float var = (redC[0] + redC[1] + redC[2] + redC[3]) * (1.f / 256.f);
  float gt = sigmoid_f(dv * rsqrtf(var + 1e-5f) * glnw[t] + glnb[t]);
  outp[b * 256 + t] = o * gt;
}

extern "C" void kernel_launch(void* const* d_in, const int* in_sizes, int n_in,
                              void* d_out, int out_size, void* d_ws, size_t ws_size,
                              hipStream_t stream)
{
  (void)in_sizes; (void)n_in; (void)out_size; (void)ws_size;
  const float* xyz   = (const float*)d_in[0];
  const float* g14d  = (const float*)d_in[1];
  const float* vf    = (const float*)d_in[2];
  const float* ext   = (const float*)d_in[3];
  const float* intr  = (const float*)d_in[4];
  const float* offs  = (const float*)d_in[5];
  const unsigned char* mask = (const unsigned char*)d_in[6];
  const float* gw1   = (const float*)d_in[7];
  const float* gb1   = (const float*)d_in[8];
  const float* gw2   = (const float*)d_in[9];
  const float* gb2   = (const float*)d_in[10];
  const float* bnw1  = (const float*)d_in[11];
  const float* bnb1  = (const float*)d_in[12];
  const float* bnw2  = (const float*)d_in[13];
  const float* bnb2  = (const float*)d_in[14];
  const float* bnlnw = (const float*)d_in[15];
  const float* bnlnb = (const float*)d_in[16];
  const float* cw    = (const float*)d_in[17];
  const float* cw2   = (const float*)d_in[18];
  const float* hw    = (const float*)d_in[19];
  const float* ln1w  = (const float*)d_in[20];
  const float* ln1b  = (const float*)d_in[21];
  const float* gww   = (const float*)d_in[22];
  const float* glnw  = (const float*)d_in[23];
  const float* glnb  = (const float*)d_in[24];

  char* ws = (char*)d_ws;
  float* vlad_acc = (float*)(ws);                            // 4*2048 f32 = 32 KB
  float* asum_acc = (float*)(ws + 32768);                    // 4*64 f32 = 1 KB
  float* proj     = (float*)(ws + 33792);                    // 24*1024*64 f32 = 6.0 MB
  float* fusedb   = (float*)(ws + 33792 + 6291456);          // 4*16384*32 f32 = 8 MB
  float* actb     = (float*)(ws + 33792 + 6291456 + 8388608);// 4*16384*64 f32 = 16 MB

  hipMemsetAsync(d_ws, 0, 33792, stream);                    // zero accumulators
  k0_proj <<<dim3(24 * 16), dim3(256), 0, stream>>>(vf, bnw1, proj);
  k1_points<<<dim3((B_ * N_) / 4), dim3(256), 0, stream>>>(
      xyz, g14d, ext, intr, offs, mask, gw1, gb1, gw2, gb2,
      proj, bnb1, bnw2, bnb2, bnlnw, bnlnb, cw, ln1w, ln1b, fusedb, actb);
  k2_vlad <<<dim3(B_ * 64), dim3(256), 0, stream>>>(fusedb, actb, vlad_acc, asum_acc);
  k3_final<<<dim3(B_), dim3(256), 0, stream>>>(vlad_acc, asum_acc, cw2, hw,
                                               gww, glnw, glnb, (float*)d_out);
}

// Round 3
// 523.350 us; speedup vs baseline: 1.2165x; 1.2165x over previous
//
#include <hip/hip_runtime.h>
#include <hip/hip_bf16.h>
#include <math.h>

// Shapes (fixed by setup_inputs): B=4, N=16384, V=6, C=384, H=W=32,
// bn hidden J=64, fused D=32, clusters K=64, out O=256.
#define B_ 4
#define N_ 16384
#define V_ 6
#define C_ 384
#define H_ 32
#define W_ 32
#define HW_ 1024

__device__ __forceinline__ float gelu_f(float x){
  return 0.5f * x * (1.0f + erff(x * 0.70710678118654752440f));
}
__device__ __forceinline__ float sigmoid_f(float x){
  return 1.0f / (1.0f + expf(-x));
}
__device__ __forceinline__ float wsum64(float v){
  #pragma unroll
  for (int m = 1; m < 64; m <<= 1) v += __shfl_xor(v, m);
  return v;
}
__device__ __forceinline__ float wmax64(float v){
  #pragma unroll
  for (int m = 1; m < 64; m <<= 1) v = fmaxf(v, __shfl_xor(v, m));
  return v;
}
__device__ __forceinline__ float wsum32(float v){
  #pragma unroll
  for (int m = 1; m < 32; m <<= 1) v += __shfl_xor(v, m);
  return v;
}

// ---------------- K0: proj[bv][pix][j] = sum_c vf[bv][c][pix] * w1[c][j] ----
// 1536 waves: wave = (bv, 16-pixel group); lane = j. vf rows via scalar loads,
// w1 via coalesced vector loads, zero LDS / zero barriers.
// grid = 384 blocks x 256
__global__ __launch_bounds__(256) void k0_proj(
    const float* __restrict__ vf, const float* __restrict__ w1,
    float* __restrict__ proj)
{
  int wid = (blockIdx.x << 2) + (threadIdx.x >> 6);
  wid = __builtin_amdgcn_readfirstlane(wid);   // wave-uniform -> SGPR
  const int lane = threadIdx.x & 63;
  const int bv  = wid >> 6;                    // 0..23
  const int px0 = (wid & 63) << 4;             // 16-pixel group
  const float* __restrict__ vbase = vf + (size_t)bv * C_ * HW_ + px0;
  float y[16];
  #pragma unroll
  for (int i = 0; i < 16; ++i) y[i] = 0.f;
  #pragma unroll 2
  for (int c = 0; c < C_; ++c){
    const float wv = w1[c * 64 + lane];        // coalesced across lanes
    const float* vr = vbase + (size_t)c * HW_; // uniform -> s_load
    #pragma unroll
    for (int i = 0; i < 16; ++i) y[i] += vr[i] * wv;
  }
  #pragma unroll
  for (int i = 0; i < 16; ++i)
    proj[((size_t)bv * HW_ + px0 + i) * 64 + lane] = y[i];
}

// ---------------- K1a: per-point scalar precompute (1 thread per point) ----
// gate MLP + camera transforms + bilinear weights/validity -> 16B record/view
// grid = 256 blocks x 256
__global__ __launch_bounds__(256) void k1a_records(
    const float* __restrict__ xyz, const float* __restrict__ g14d,
    const float* __restrict__ ext, const float* __restrict__ intr,
    const float* __restrict__ offs, const unsigned char* __restrict__ mask,
    const float* __restrict__ gw1, const float* __restrict__ gb1,
    const float* __restrict__ gw2, const float* __restrict__ gb2,
    uint4* __restrict__ rec, float* __restrict__ gate_g,
    float* __restrict__ summ_g)
{
  const int p = blockIdx.x * 256 + threadIdx.x;   // 0..65535
  const int b = p >> 14;

  // physics gate (identical op order to the passing r2 kernel)
  const float* g = g14d + (size_t)p * 14;
  float in0 = fminf(fmaxf(g[4],  0.01f), 10.f);
  float in1 = fminf(fmaxf(g[5],  0.01f), 10.f);
  float in2 = fminf(fmaxf(g[6],  0.01f), 10.f);
  float in3 = fminf(fmaxf(g[11], 0.0f),  1.f);
  float gacc = gb2[0];
  #pragma unroll
  for (int hh = 0; hh < 16; ++hh){
    float tv = gb1[hh] + in0 * gw1[hh] + in1 * gw1[16 + hh]
             + in2 * gw1[32 + hh] + in3 * gw1[48 + hh];
    gacc += gelu_f(tv) * gw2[hh];
  }
  gate_g[p] = sigmoid_f(gacc);

  const float px = xyz[p * 3], py = xyz[p * 3 + 1], pz = xyz[p * 3 + 2];
  const float offx = offs[p * 2], offy = offs[p * 2 + 1];
  const float mval = mask[p] ? 1.f : 0.f;

  float summ = 0.f;
  #pragma unroll
  for (int v = 0; v < V_; ++v){
    const float* E = ext  + (size_t)(b * V_ + v) * 12;
    const float* I = intr + (size_t)(b * V_ + v) * 9;
    float c0 = E[0]*px + E[1]*py + E[2]*pz + E[3];
    float c1 = E[4]*px + E[5]*py + E[6]*pz + E[7];
    float c2 = E[8]*px + E[9]*py + E[10]*pz + E[11];
    float u0 = I[0]*c0 + I[1]*c1 + I[2]*c2;
    float u1 = I[3]*c0 + I[4]*c1 + I[5]*c2;
    float u2 = I[6]*c0 + I[7]*c1 + I[8]*c2;
    float depth = fmaxf(u2, 1e-6f);
    float gx = 2.0f * (u0 / depth) / (W_ * 14.0f) - 1.0f + offx;
    float gy = 2.0f * (u1 / depth) / (H_ * 14.0f) - 1.0f + offy;
    float fx = ((gx + 1.0f) * W_ - 1.0f) * 0.5f;
    float fy = ((gy + 1.0f) * H_ - 1.0f) * 0.5f;
    fx = fminf(fmaxf(fx, -4.0f), 36.0f);
    fy = fminf(fmaxf(fy, -4.0f), 36.0f);
    float fx0 = floorf(fx), fy0 = floorf(fy);
    float wx = fx - fx0, wy = fy - fy0;
    int x0 = (int)fx0, y0 = (int)fy0;
    unsigned vx0 = (x0 >= 0 && x0 < W_), vx1 = (x0 + 1 >= 0 && x0 + 1 < W_);
    unsigned vy0 = (y0 >= 0 && y0 < H_), vy1 = (y0 + 1 >= 0 && y0 + 1 < H_);
    unsigned vbits = (vx0 & vy0) | ((vx1 & vy0) << 1)
                   | ((vx0 & vy1) << 2) | ((vx1 & vy1) << 3);
    float vm = (depth > 0.1f && fabsf(gx) <= 1.0f && fabsf(gy) <= 1.0f) ? mval : 0.f;
    summ += vm;
    unsigned pk = (unsigned)(x0 + 8) | ((unsigned)(y0 + 8) << 8)
                | (vbits << 16) | ((vm > 0.f ? 1u : 0u) << 20);
    uint4 r;
    r.x = __float_as_uint(wx); r.y = __float_as_uint(wy); r.z = pk; r.w = 0u;
    rec[(size_t)v * (B_ * N_) + p] = r;                 // coalesced per view
  }
  summ_g[p] = summ;
}

// ---------------- K1b: per-point vector work (1 wave per point) ------------
// No LDS, no barriers; h-broadcast via width-32 shuffles; w2 column in regs.
// grid = 16384 blocks x 256 (4 waves)
__global__ __launch_bounds__(256) void k1b_points(
    const uint4* __restrict__ rec, const float* __restrict__ gate_g,
    const float* __restrict__ summ_g, const unsigned char* __restrict__ mask,
    const float* __restrict__ proj,
    const float* __restrict__ b1, const float* __restrict__ w2,
    const float* __restrict__ b2, const float* __restrict__ lnw,
    const float* __restrict__ lnb, const float* __restrict__ cw,
    const float* __restrict__ ln1w, const float* __restrict__ ln1b,
    float* __restrict__ fused_out, float* __restrict__ act_out)
{
  const int wave = threadIdx.x >> 6, lane = threadIdx.x & 63;
  const int p = (blockIdx.x << 2) + wave;
  const int b = p >> 14;
  const int d = lane & 31, half = lane >> 5;

  float w2c[32];
  #pragma unroll
  for (int j = 0; j < 32; ++j) w2c[j] = w2[(half * 32 + j) * 32 + d];
  const float b1v = b1[lane], b2v = b2[d], lnwv = lnw[d], lnbv = lnb[d];
  const float gate = gate_g[p];
  const float summ = summ_g[p];
  const float mval = mask[p] ? 1.f : 0.f;
  const float* __restrict__ prb = proj + (size_t)b * V_ * HW_ * 64;

  float sum_f = 0.f;
  #pragma unroll
  for (int v = 0; v < V_; ++v){
    const uint4 r = rec[(size_t)v * (B_ * N_) + p];     // wave-uniform 16B
    const float wx = __uint_as_float(r.x), wy = __uint_as_float(r.y);
    const unsigned pk = r.z;
    const int x0 = (int)(pk & 0xFF) - 8, y0 = (int)((pk >> 8) & 0xFF) - 8;
    const float v00 = (float)((pk >> 16) & 1), v10 = (float)((pk >> 17) & 1);
    const float v01 = (float)((pk >> 18) & 1), v11 = (float)((pk >> 19) & 1);
    const float vmf = (float)((pk >> 20) & 1);
    const int x0c = min(max(x0, 0), W_ - 1), x1c = min(max(x0 + 1, 0), W_ - 1);
    const int y0c = min(max(y0, 0), H_ - 1), y1c = min(max(y0 + 1, 0), H_ - 1);
    const float* pr = prb + (size_t)v * HW_ * 64;
    // weight*validity is exact (validity in {0,1}); op order matches r2 kernel
    float s = ((1.f - wx) * (1.f - wy) * v00) * pr[(y0c * W_ + x0c) * 64 + lane];
    s += (wx * (1.f - wy) * v10) * pr[(y0c * W_ + x1c) * 64 + lane];
    s += ((1.f - wx) * wy * v01) * pr[(y1c * W_ + x0c) * 64 + lane];
    s += (wx * wy * v11) * pr[(y1c * W_ + x1c) * 64 + lane];
    const float h = gelu_f(s + b1v);
    float yp = 0.f;
    #pragma unroll
    for (int j = 0; j < 32; ++j)
      yp += __shfl(h, j, 32) * w2c[j];        // group-relative broadcast
    float yv = yp + __shfl_xor(yp, 32) + b2v;
    float mean = wsum32(yv) * (1.f / 32.f);
    float dv = yv - mean;
    float var = wsum32(dv * dv) * (1.f / 32.f);
    float v32 = dv * rsqrtf(var + 1e-5f) * lnwv + lnbv;
    sum_f += v32 * gate * vmf;                // same two-mul form as r2
  }
  const float fu = sum_f / (summ + 1e-6f);
  if (lane < 32) fused_out[(size_t)p * 32 + lane] = fu;

  // act = softmax(LN(fused @ cw)) * mask ; lane = cluster k
  float z = 0.f;
  #pragma unroll
  for (int dd = 0; dd < 32; ++dd)
    z += __shfl(fu, dd, 32) * cw[dd * 64 + lane];
  float mean = wsum64(z) * (1.f / 64.f);
  float dz = z - mean;
  float var = wsum64(dz * dz) * (1.f / 64.f);
  float zl = dz * rsqrtf(var + 1e-5f) * ln1w[lane] + ln1b[lane];
  float mx = wmax64(zl);
  float e = expf(zl - mx);
  float ssum = wsum64(e);
  act_out[(size_t)p * 64 + lane] = (e / ssum) * mval;
}

// ---------------- K2: vlad[b,d,k] += sum_n act*fused ; asum[b,k] += act ----
// grid = B * 64 segments (256 points each); block = 256   (unchanged from r2)
__global__ __launch_bounds__(256) void k2_vlad(
    const float* __restrict__ fused, const float* __restrict__ act,
    float* __restrict__ vlad_acc, float* __restrict__ asum_acc)
{
  __shared__ float act_s[64][64];
  __shared__ float fu_s[64][32];
  const int b = blockIdx.x >> 6, seg = blockIdx.x & 63;
  const int n0 = seg * 256;
  const int t = threadIdx.x, k = t & 63, dg = t >> 6;
  float vacc[8];
  #pragma unroll
  for (int r = 0; r < 8; ++r) vacc[r] = 0.f;
  float asum = 0.f;

  for (int sc = 0; sc < 4; ++sc){
    int nb = n0 + sc * 64;
    #pragma unroll
    for (int i = 0; i < 16; ++i){
      int idx = t + i * 256;
      act_s[idx >> 6][idx & 63] =
        act[((size_t)((b << 14) + nb + (idx >> 6))) * 64 + (idx & 63)];
    }
    #pragma unroll
    for (int i = 0; i < 8; ++i){
      int idx = t + i * 256;
      fu_s[idx >> 5][idx & 31] =
        fused[((size_t)((b << 14) + nb + (idx >> 5))) * 32 + (idx & 31)];
    }
    __syncthreads();
    for (int i = 0; i < 64; ++i){
      float a = act_s[i][k];
      const float* fr = &fu_s[i][dg * 8];
      #pragma unroll
      for (int r = 0; r < 8; ++r) vacc[r] += a * fr[r];
      if (dg == 0) asum += a;
    }
    __syncthreads();
  }
  #pragma unroll
  for (int r = 0; r < 8; ++r)
    atomicAdd(&vlad_acc[b * 2048 + (dg * 8 + r) * 64 + k], vacc[r]);
  if (dg == 0) atomicAdd(&asum_acc[b * 64 + k], asum);
}

// ---------------- K3: finalize per batch (unchanged from r2) ---------------
__global__ __launch_bounds__(256) void k3_final(
    const float* __restrict__ vlad_acc, const float* __restrict__ asum_acc,
    const float* __restrict__ cw2, const float* __restrict__ hw,
    const float* __restrict__ gww, const float* __restrict__ glnw,
    const float* __restrict__ glnb, float* __restrict__ outp)
{
  const int b = blockIdx.x, t = threadIdx.x;
  __shared__ float vs[2048];
  __shared__ float denom[64];
  __shared__ float redA[4], redB[4], redC[4];
  __shared__ float out_s[256];

  #pragma unroll
  for (int i = 0; i < 8; ++i){
    int idx = t + i * 256;
    vs[idx] = vlad_acc[b * 2048 + idx]
            - asum_acc[b * 64 + (idx & 63)] * cw2[idx];
  }
  __syncthreads();
  if (t < 64){
    float ss = 0.f;
    #pragma unroll
    for (int dd = 0; dd < 32; ++dd){ float x = vs[dd * 64 + t]; ss += x * x; }
    denom[t] = fmaxf(sqrtf(ss), 1e-12f);
  }
  __syncthreads();
  float ls = 0.f;
  #pragma unroll
  for (int i = 0; i < 8; ++i){
    int idx = t + i * 256;
    float x = vs[idx] / denom[idx & 63];
    vs[idx] = x;
    ls += x * x;
  }
  ls = wsum64(ls);
  if ((t & 63) == 0) redA[t >> 6] = ls;
  __syncthreads();
  float tot = redA[0] + redA[1] + redA[2] + redA[3];
  float ginv = 1.0f / fmaxf(sqrtf(tot), 1e-12f);
  float acc = 0.f;
  for (int idx = 0; idx < 2048; ++idx)
    acc += vs[idx] * hw[(size_t)idx * 256 + t];
  float o = acc * ginv;
  out_s[t] = o;
  __syncthreads();
  float gp = 0.f;
  for (int i = 0; i < 256; ++i) gp += out_s[i] * gww[i * 256 + t];
  float s1 = wsum64(gp);
  if ((t & 63) == 0) redB[t >> 6] = s1;
  __syncthreads();
  float mean = (redB[0] + redB[1] + redB[2] + redB[3]) * (1.f / 256.f);
  float dv = gp - mean;
  float s2 = wsum64(dv * dv);
  if ((t & 63) == 0) redC[t >> 6] = s2;
  __syncthreads();
  float var = (redC[0] + redC[1] + redC[2] + redC[3]) * (1.f / 256.f);
  float gt = sigmoid_f(dv * rsqrtf(var + 1e-5f) * glnw[t] + glnb[t]);
  outp[b * 256 + t] = o * gt;
}

extern "C" void kernel_launch(void* const* d_in, const int* in_sizes, int n_in,
                              void* d_out, int out_size, void* d_ws, size_t ws_size,
                              hipStream_t stream)
{
  (void)in_sizes; (void)n_in; (void)out_size; (void)ws_size;
  const float* xyz   = (const float*)d_in[0];
  const float* g14d  = (const float*)d_in[1];
  const float* vf    = (const float*)d_in[2];
  const float* ext   = (const float*)d_in[3];
  const float* intr  = (const float*)d_in[4];
  const float* offs  = (const float*)d_in[5];
  const unsigned char* mask = (const unsigned char*)d_in[6];
  const float* gw1   = (const float*)d_in[7];
  const float* gb1   = (const float*)d_in[8];
  const float* gw2   = (const float*)d_in[9];
  const float* gb2   = (const float*)d_in[10];
  const float* bnw1  = (const float*)d_in[11];
  const float* bnb1  = (const float*)d_in[12];
  const float* bnw2  = (const float*)d_in[13];
  const float* bnb2  = (const float*)d_in[14];
  const float* bnlnw = (const float*)d_in[15];
  const float* bnlnb = (const float*)d_in[16];
  const float* cw    = (const float*)d_in[17];
  const float* cw2   = (const float*)d_in[18];
  const float* hw    = (const float*)d_in[19];
  const float* ln1w  = (const float*)d_in[20];
  const float* ln1b  = (const float*)d_in[21];
  const float* gww   = (const float*)d_in[22];
  const float* glnw  = (const float*)d_in[23];
  const float* glnb  = (const float*)d_in[24];

  char* ws = (char*)d_ws;
  float* vlad_acc = (float*)(ws);                      // 32 KB
  float* asum_acc = (float*)(ws + 32768);              // 1 KB
  float* proj     = (float*)(ws + 33792);              // 6.29 MB
  float* fusedb   = (float*)(ws + 6325248);            // 8 MB
  float* actb     = (float*)(ws + 14713856);           // 16 MB
  uint4* recb     = (uint4*)(ws + 31491072);           // 6.29 MB
  float* gate_g   = (float*)(ws + 37782528);           // 256 KB
  float* summ_g   = (float*)(ws + 38044672);           // 256 KB  (end ~36.5 MB)

  hipMemsetAsync(d_ws, 0, 33792, stream);              // zero accumulators
  k0_proj    <<<dim3(384),   dim3(256), 0, stream>>>(vf, bnw1, proj);
  k1a_records<<<dim3(256),   dim3(256), 0, stream>>>(
      xyz, g14d, ext, intr, offs, mask, gw1, gb1, gw2, gb2,
      recb, gate_g, summ_g);
  k1b_points <<<dim3(16384), dim3(256), 0, stream>>>(
      recb, gate_g, summ_g, mask, proj,
      bnb1, bnw2, bnb2, bnlnw, bnlnb, cw, ln1w, ln1b, fusedb, actb);
  k2_vlad    <<<dim3(B_ * 64), dim3(256), 0, stream>>>(fusedb, actb, vlad_acc, asum_acc);
  k3_final   <<<dim3(B_),    dim3(256), 0, stream>>>(vlad_acc, asum_acc, cw2, hw,
                                                     gww, glnw, glnb, (float*)d_out);
}

// Round 5
// 363.373 us; speedup vs baseline: 1.7521x; 1.4403x over previous
//
#include <hip/hip_runtime.h>
#include <hip/hip_bf16.h>
#include <math.h>

// Shapes (fixed by setup_inputs): B=4, N=16384, V=6, C=384, H=W=32
#define B_ 4
#define N_ 16384
#define V_ 6
#define C_ 384
#define H_ 32
#define W_ 32
#define HW_ 1024

__device__ __forceinline__ float gelu_f(float x){
  return 0.5f * x * (1.0f + erff(x * 0.70710678118654752440f));
}
__device__ __forceinline__ float sigmoid_f(float x){
  return 1.0f / (1.0f + expf(-x));
}
__device__ __forceinline__ float wsum64(float v){
  #pragma unroll
  for (int m = 1; m < 64; m <<= 1) v += __shfl_xor(v, m);
  return v;
}
__device__ __forceinline__ float wmax64(float v){
  #pragma unroll
  for (int m = 1; m < 64; m <<= 1) v = fmaxf(v, __shfl_xor(v, m));
  return v;
}
__device__ __forceinline__ float wsum32(float v){
  #pragma unroll
  for (int m = 1; m < 32; m <<= 1) v += __shfl_xor(v, m);
  return v;
}

// ---------------- K0: proj[bv][pix][j] = sum_c vf[bv][c][pix] * w1[c][j] ----
// grid = 24 bv * 32 px-tiles(32 px) = 768 blocks; block = 512 (8 waves)
// LDS-staged 64c x 32px chunks; per-c: 1 coalesced w1 load + 1 broadcast
// ds_read_b128 + 4 FMA per thread.
__global__ __launch_bounds__(512) void k0_proj(
    const float* __restrict__ vf, const float* __restrict__ w1,
    float* __restrict__ proj)
{
  const int bv  = blockIdx.x >> 5;             // 0..23
  const int px0 = (blockIdx.x & 31) << 5;      // 32-pixel tile
  __shared__ float fs[64][32];                 // 8 KB chunk
  const int t = threadIdx.x;
  const int j = t & 63;                        // output channel
  const int pg = t >> 6;                       // 0..7 -> 4-pixel group
  const int sc = t >> 3, sq = t & 7;           // staging: c-row, px-quad
  float acc0 = 0.f, acc1 = 0.f, acc2 = 0.f, acc3 = 0.f;

  for (int c0 = 0; c0 < C_; c0 += 64){
    const float4 sv = *(const float4*)&vf[((size_t)bv * C_ + c0 + sc) * HW_
                                          + px0 + sq * 4];
    __syncthreads();                           // prev-chunk readers done
    *(float4*)&fs[sc][sq * 4] = sv;
    __syncthreads();                           // chunk visible
    for (int c = 0; c < 64; ++c){
      const float w = w1[(c0 + c) * 64 + j];   // coalesced 256B across lanes
      const float4 hv = *(const float4*)&fs[c][pg * 4];  // wave-uniform bcast
      acc0 += hv.x * w;
      acc1 += hv.y * w;
      acc2 += hv.z * w;
      acc3 += hv.w * w;
    }
  }
  const size_t ob = ((size_t)bv * HW_ + px0 + pg * 4) * 64 + j;
  proj[ob]           = acc0;
  proj[ob + 64]      = acc1;
  proj[ob + 128]     = acc2;
  proj[ob + 192]     = acc3;
}

// ---------------- K1a: per-point scalar precompute (1 thread per point) ----
__global__ __launch_bounds__(256) void k1a_records(
    const float* __restrict__ xyz, const float* __restrict__ g14d,
    const float* __restrict__ ext, const float* __restrict__ intr,
    const float* __restrict__ offs, const unsigned char* __restrict__ mask,
    const float* __restrict__ gw1, const float* __restrict__ gb1,
    const float* __restrict__ gw2, const float* __restrict__ gb2,
    uint4* __restrict__ rec, float* __restrict__ gate_g,
    float* __restrict__ summ_g)
{
  const int p = blockIdx.x * 256 + threadIdx.x;   // 0..65535
  const int b = p >> 14;

  const float* g = g14d + (size_t)p * 14;
  float in0 = fminf(fmaxf(g[4],  0.01f), 10.f);
  float in1 = fminf(fmaxf(g[5],  0.01f), 10.f);
  float in2 = fminf(fmaxf(g[6],  0.01f), 10.f);
  float in3 = fminf(fmaxf(g[11], 0.0f),  1.f);
  float gacc = gb2[0];
  #pragma unroll
  for (int hh = 0; hh < 16; ++hh){
    float tv = gb1[hh] + in0 * gw1[hh] + in1 * gw1[16 + hh]
             + in2 * gw1[32 + hh] + in3 * gw1[48 + hh];
    gacc += gelu_f(tv) * gw2[hh];
  }
  gate_g[p] = sigmoid_f(gacc);

  const float px = xyz[p * 3], py = xyz[p * 3 + 1], pz = xyz[p * 3 + 2];
  const float offx = offs[p * 2], offy = offs[p * 2 + 1];
  const float mval = mask[p] ? 1.f : 0.f;

  float summ = 0.f;
  #pragma unroll
  for (int v = 0; v < V_; ++v){
    const float* E = ext  + (size_t)(b * V_ + v) * 12;
    const float* I = intr + (size_t)(b * V_ + v) * 9;
    float c0 = E[0]*px + E[1]*py + E[2]*pz + E[3];
    float c1 = E[4]*px + E[5]*py + E[6]*pz + E[7];
    float c2 = E[8]*px + E[9]*py + E[10]*pz + E[11];
    float u0 = I[0]*c0 + I[1]*c1 + I[2]*c2;
    float u1 = I[3]*c0 + I[4]*c1 + I[5]*c2;
    float u2 = I[6]*c0 + I[7]*c1 + I[8]*c2;
    float depth = fmaxf(u2, 1e-6f);
    float gx = 2.0f * (u0 / depth) / (W_ * 14.0f) - 1.0f + offx;
    float gy = 2.0f * (u1 / depth) / (H_ * 14.0f) - 1.0f + offy;
    float fx = ((gx + 1.0f) * W_ - 1.0f) * 0.5f;
    float fy = ((gy + 1.0f) * H_ - 1.0f) * 0.5f;
    fx = fminf(fmaxf(fx, -4.0f), 36.0f);
    fy = fminf(fmaxf(fy, -4.0f), 36.0f);
    float fx0 = floorf(fx), fy0 = floorf(fy);
    float wx = fx - fx0, wy = fy - fy0;
    int x0 = (int)fx0, y0 = (int)fy0;
    unsigned vx0 = (x0 >= 0 && x0 < W_), vx1 = (x0 + 1 >= 0 && x0 + 1 < W_);
    unsigned vy0 = (y0 >= 0 && y0 < H_), vy1 = (y0 + 1 >= 0 && y0 + 1 < H_);
    unsigned vbits = (vx0 & vy0) | ((vx1 & vy0) << 1)
                   | ((vx0 & vy1) << 2) | ((vx1 & vy1) << 3);
    float vm = (depth > 0.1f && fabsf(gx) <= 1.0f && fabsf(gy) <= 1.0f) ? mval : 0.f;
    summ += vm;
    unsigned pk = (unsigned)(x0 + 8) | ((unsigned)(y0 + 8) << 8)
                | (vbits << 16) | ((vm > 0.f ? 1u : 0u) << 20);
    uint4 r;
    r.x = __float_as_uint(wx); r.y = __float_as_uint(wy); r.z = pk; r.w = 0u;
    rec[(size_t)v * (B_ * N_) + p] = r;
  }
  summ_g[p] = summ;
}

// ---------------- K1b: per-point vector work (1 wave per point) ------------
// h broadcast via wave-internal LDS write + 8x uniform ds_read_b128
// (in-order DS pipe within a wave; compiler fence only, no barrier).
// grid = 16384 blocks x 256 (4 waves)
__global__ __launch_bounds__(256) void k1b_points(
    const uint4* __restrict__ rec, const float* __restrict__ gate_g,
    const float* __restrict__ summ_g, const unsigned char* __restrict__ mask,
    const float* __restrict__ proj,
    const float* __restrict__ b1, const float* __restrict__ w2,
    const float* __restrict__ b2, const float* __restrict__ lnw,
    const float* __restrict__ lnb, const float* __restrict__ cw,
    const float* __restrict__ ln1w, const float* __restrict__ ln1b,
    float* __restrict__ fused_out, float* __restrict__ act_out)
{
  __shared__ float h_s[4][64];
  __shared__ float fu_s[4][32];
  const int wave = threadIdx.x >> 6, lane = threadIdx.x & 63;
  const int p = (blockIdx.x << 2) + wave;
  const int b = p >> 14;
  const int d = lane & 31, half = lane >> 5;

  float w2c[32];
  #pragma unroll
  for (int j = 0; j < 32; ++j) w2c[j] = w2[(half * 32 + j) * 32 + d];
  const float b1v = b1[lane], b2v = b2[d], lnwv = lnw[d], lnbv = lnb[d];
  const float gate = gate_g[p];
  const float summ = summ_g[p];
  const float mval = mask[p] ? 1.f : 0.f;
  const float* __restrict__ prb = proj + (size_t)b * V_ * HW_ * 64;

  float sum_f = 0.f;
  #pragma unroll
  for (int v = 0; v < V_; ++v){
    const uint4 r = rec[(size_t)v * (B_ * N_) + p];     // wave-uniform 16B
    const float wx = __uint_as_float(r.x), wy = __uint_as_float(r.y);
    const unsigned pk = r.z;
    const int x0 = (int)(pk & 0xFF) - 8, y0 = (int)((pk >> 8) & 0xFF) - 8;
    const float v00 = (float)((pk >> 16) & 1), v10 = (float)((pk >> 17) & 1);
    const float v01 = (float)((pk >> 18) & 1), v11 = (float)((pk >> 19) & 1);
    const float vmf = (float)((pk >> 20) & 1);
    const int x0c = min(max(x0, 0), W_ - 1), x1c = min(max(x0 + 1, 0), W_ - 1);
    const int y0c = min(max(y0, 0), H_ - 1), y1c = min(max(y0 + 1, 0), H_ - 1);
    const float* pr = prb + (size_t)v * HW_ * 64;
    float s = ((1.f - wx) * (1.f - wy) * v00) * pr[(y0c * W_ + x0c) * 64 + lane];
    s += (wx * (1.f - wy) * v10) * pr[(y0c * W_ + x1c) * 64 + lane];
    s += ((1.f - wx) * wy * v01) * pr[(y1c * W_ + x0c) * 64 + lane];
    s += (wx * wy * v11) * pr[(y1c * W_ + x1c) * 64 + lane];
    const float h = gelu_f(s + b1v);

    h_s[wave][lane] = h;
    asm volatile("" ::: "memory");              // order write before reads
    const float4* hp = reinterpret_cast<const float4*>(&h_s[wave][half * 32]);
    float yp = 0.f;
    #pragma unroll
    for (int q = 0; q < 8; ++q){
      const float4 hv = hp[q];                  // uniform addr -> broadcast
      yp += hv.x * w2c[4 * q + 0];
      yp += hv.y * w2c[4 * q + 1];
      yp += hv.z * w2c[4 * q + 2];
      yp += hv.w * w2c[4 * q + 3];
    }
    float yv = yp + __shfl_xor(yp, 32) + b2v;
    float mean = wsum32(yv) * (1.f / 32.f);
    float dv = yv - mean;
    float var = wsum32(dv * dv) * (1.f / 32.f);
    float v32 = dv * rsqrtf(var + 1e-5f) * lnwv + lnbv;
    sum_f += v32 * gate * vmf;
    asm volatile("" ::: "memory");              // reads done before next write
  }
  const float fu = sum_f / (summ + 1e-6f);
  if (lane < 32){
    fu_s[wave][lane] = fu;
    fused_out[(size_t)p * 32 + lane] = fu;
  }
  asm volatile("" ::: "memory");

  // act = softmax(LN(fused @ cw)) * mask ; lane = cluster k
  const float4* fp = reinterpret_cast<const float4*>(&fu_s[wave][0]);
  float z = 0.f;
  #pragma unroll
  for (int q = 0; q < 8; ++q){
    const float4 fv = fp[q];                    // uniform addr -> broadcast
    z += fv.x * cw[(4 * q + 0) * 64 + lane];
    z += fv.y * cw[(4 * q + 1) * 64 + lane];
    z += fv.z * cw[(4 * q + 2) * 64 + lane];
    z += fv.w * cw[(4 * q + 3) * 64 + lane];
  }
  float mean = wsum64(z) * (1.f / 64.f);
  float dz = z - mean;
  float var = wsum64(dz * dz) * (1.f / 64.f);
  float zl = dz * rsqrtf(var + 1e-5f) * ln1w[lane] + ln1b[lane];
  float mx = wmax64(zl);
  float e = expf(zl - mx);
  float ssum = wsum64(e);
  act_out[(size_t)p * 64 + lane] = (e / ssum) * mval;
}

// ---------------- K2: vlad[b,d,k] += sum_n act*fused ; asum[b,k] += act ----
__global__ __launch_bounds__(256) void k2_vlad(
    const float* __restrict__ fused, const float* __restrict__ act,
    float* __restrict__ vlad_acc, float* __restrict__ asum_acc)
{
  __shared__ float act_s[64][64];
  __shared__ float fu_s[64][32];
  const int b = blockIdx.x >> 6, seg = blockIdx.x & 63;
  const int n0 = seg * 256;
  const int t = threadIdx.x, k = t & 63, dg = t >> 6;
  float vacc[8];
  #pragma unroll
  for (int r = 0; r < 8; ++r) vacc[r] = 0.f;
  float asum = 0.f;

  for (int sc = 0; sc < 4; ++sc){
    int nb = n0 + sc * 64;
    #pragma unroll
    for (int i = 0; i < 16; ++i){
      int idx = t + i * 256;
      act_s[idx >> 6][idx & 63] =
        act[((size_t)((b << 14) + nb + (idx >> 6))) * 64 + (idx & 63)];
    }
    #pragma unroll
    for (int i = 0; i < 8; ++i){
      int idx = t + i * 256;
      fu_s[idx >> 5][idx & 31] =
        fused[((size_t)((b << 14) + nb + (idx >> 5))) * 32 + (idx & 31)];
    }
    __syncthreads();
    for (int i = 0; i < 64; ++i){
      float a = act_s[i][k];
      const float* fr = &fu_s[i][dg * 8];
      #pragma unroll
      for (int r = 0; r < 8; ++r) vacc[r] += a * fr[r];
      if (dg == 0) asum += a;
    }
    __syncthreads();
  }
  #pragma unroll
  for (int r = 0; r < 8; ++r)
    atomicAdd(&vlad_acc[b * 2048 + (dg * 8 + r) * 64 + k], vacc[r]);
  if (dg == 0) atomicAdd(&asum_acc[b * 64 + k], asum);
}

// ---------------- K3a: subtract + intra-norm + global-norm factor ---------
__global__ __launch_bounds__(256) void k3a_norm(
    const float* __restrict__ vlad_acc, const float* __restrict__ asum_acc,
    const float* __restrict__ cw2, float* __restrict__ vs1_g,
    float* __restrict__ ginv_g)
{
  const int b = blockIdx.x, t = threadIdx.x;
  __shared__ float vs[2048];
  __shared__ float denom[64];
  __shared__ float redA[4];
  #pragma unroll
  for (int i = 0; i < 8; ++i){
    int idx = t + i * 256;
    vs[idx] = vlad_acc[b * 2048 + idx]
            - asum_acc[b * 64 + (idx & 63)] * cw2[idx];
  }
  __syncthreads();
  if (t < 64){
    float ss = 0.f;
    #pragma unroll
    for (int dd = 0; dd < 32; ++dd){ float x = vs[dd * 64 + t]; ss += x * x; }
    denom[t] = fmaxf(sqrtf(ss), 1e-12f);
  }
  __syncthreads();
  float ls = 0.f;
  #pragma unroll
  for (int i = 0; i < 8; ++i){
    int idx = t + i * 256;
    float x = vs[idx] / denom[idx & 63];
    vs1_g[b * 2048 + idx] = x;
    ls += x * x;
  }
  ls = wsum64(ls);
  if ((t & 63) == 0) redA[t >> 6] = ls;
  __syncthreads();
  if (t == 0){
    float tot = redA[0] + redA[1] + redA[2] + redA[3];
    ginv_g[b] = 1.0f / fmaxf(sqrtf(tot), 1e-12f);
  }
}

// ---------------- K3b: out_acc[b,o] += vs1-slice @ hw-slice ---------------
// grid = 4 b x 8 K-slices = 32 blocks x 256
__global__ __launch_bounds__(256) void k3b_hw(
    const float* __restrict__ vs1_g, const float* __restrict__ hw,
    float* __restrict__ out_acc)
{
  const int b = blockIdx.x >> 3, ks = blockIdx.x & 7;
  const int t = threadIdx.x;
  __shared__ float xs[256];
  xs[t] = vs1_g[b * 2048 + ks * 256 + t];
  __syncthreads();
  float acc = 0.f;
  #pragma unroll 4
  for (int i = 0; i < 256; ++i)
    acc += xs[i] * hw[(size_t)(ks * 256 + i) * 256 + t];
  atomicAdd(&out_acc[b * 256 + t], acc);
}

// ---------------- K3c: gating LN + final output ---------------------------
__global__ __launch_bounds__(256) void k3c_gate(
    const float* __restrict__ out_acc, const float* __restrict__ ginv_g,
    const float* __restrict__ gww, const float* __restrict__ glnw,
    const float* __restrict__ glnb, float* __restrict__ outp)
{
  const int b = blockIdx.x, t = threadIdx.x;
  __shared__ float out_s[256];
  __shared__ float redB[4], redC[4];
  const float ginv = ginv_g[b];
  const float o = out_acc[b * 256 + t] * ginv;
  out_s[t] = o;
  __syncthreads();
  float gp = 0.f;
  #pragma unroll 4
  for (int i = 0; i < 256; ++i) gp += out_s[i] * gww[i * 256 + t];
  float s1 = wsum64(gp);
  if ((t & 63) == 0) redB[t >> 6] = s1;
  __syncthreads();
  float mean = (redB[0] + redB[1] + redB[2] + redB[3]) * (1.f / 256.f);
  float dv = gp - mean;
  float s2 = wsum64(dv * dv);
  if ((t & 63) == 0) redC[t >> 6] = s2;
  __syncthreads();
  float var = (redC[0] + redC[1] + redC[2] + redC[3]) * (1.f / 256.f);
  float gt = sigmoid_f(dv * rsqrtf(var + 1e-5f) * glnw[t] + glnb[t]);
  outp[b * 256 + t] = o * gt;
}

extern "C" void kernel_launch(void* const* d_in, const int* in_sizes, int n_in,
                              void* d_out, int out_size, void* d_ws, size_t ws_size,
                              hipStream_t stream)
{
  (void)in_sizes; (void)n_in; (void)out_size; (void)ws_size;
  const float* xyz   = (const float*)d_in[0];
  const float* g14d  = (const float*)d_in[1];
  const float* vf    = (const float*)d_in[2];
  const float* ext   = (const float*)d_in[3];
  const float* intr  = (const float*)d_in[4];
  const float* offs  = (const float*)d_in[5];
  const unsigned char* mask = (const unsigned char*)d_in[6];
  const float* gw1   = (const float*)d_in[7];
  const float* gb1   = (const float*)d_in[8];
  const float* gw2   = (const float*)d_in[9];
  const float* gb2   = (const float*)d_in[10];
  const float* bnw1  = (const float*)d_in[11];
  const float* bnb1  = (const float*)d_in[12];
  const float* bnw2  = (const float*)d_in[13];
  const float* bnb2  = (const float*)d_in[14];
  const float* bnlnw = (const float*)d_in[15];
  const float* bnlnb = (const float*)d_in[16];
  const float* cw    = (const float*)d_in[17];
  const float* cw2   = (const float*)d_in[18];
  const float* hw    = (const float*)d_in[19];
  const float* ln1w  = (const float*)d_in[20];
  const float* ln1b  = (const float*)d_in[21];
  const float* gww   = (const float*)d_in[22];
  const float* glnw  = (const float*)d_in[23];
  const float* glnb  = (const float*)d_in[24];

  char* ws = (char*)d_ws;
  // layout identical footprint to r3 (38,306,816 B total)
  float* vlad_acc = (float*)(ws);                      // 32 KB
  float* asum_acc = (float*)(ws + 32768);              // 1 KB
  float* proj     = (float*)(ws + 33792);              // 6.29 MB
  float* fusedb   = (float*)(ws + 6325248);            // 8 MB
  float* actb     = (float*)(ws + 14713856);           // 16 MB
  uint4* recb     = (uint4*)(ws + 31491072);           // 6.29 MB (k1 phase)
  float* gate_g   = (float*)(ws + 37782528);           // 256 KB
  float* summ_g   = (float*)(ws + 38044672);           // 256 KB
  // k3-phase aliases inside the (dead after k1b) rec region:
  float* ginv_g   = (float*)(ws + 31491072);           // 256 B
  float* vs1_g    = (float*)(ws + 31491328);           // 32 KB
  float* out_acc  = (float*)(ws + 31524096);           // 4 KB

  hipMemsetAsync(d_ws, 0, 33792, stream);              // zero vlad/asum
  k0_proj    <<<dim3(768),   dim3(512), 0, stream>>>(vf, bnw1, proj);
  k1a_records<<<dim3(256),   dim3(256), 0, stream>>>(
      xyz, g14d, ext, intr, offs, mask, gw1, gb1, gw2, gb2,
      recb, gate_g, summ_g);
  k1b_points <<<dim3(16384), dim3(256), 0, stream>>>(
      recb, gate_g, summ_g, mask, proj,
      bnb1, bnw2, bnb2, bnlnw, bnlnb, cw, ln1w, ln1b, fusedb, actb);
  k2_vlad    <<<dim3(B_ * 64), dim3(256), 0, stream>>>(fusedb, actb, vlad_acc, asum_acc);
  hipMemsetAsync(ws + 31524096, 0, 4096, stream);      // zero out_acc (rec dead now)
  k3a_norm   <<<dim3(B_),    dim3(256), 0, stream>>>(vlad_acc, asum_acc, cw2,
                                                     vs1_g, ginv_g);
  k3b_hw     <<<dim3(32),    dim3(256), 0, stream>>>(vs1_g, hw, out_acc);
  k3c_gate   <<<dim3(B_),    dim3(256), 0, stream>>>(out_acc, ginv_g, gww,
                                                     glnw, glnb, (float*)d_out);
}